// Round 9
// baseline (481.478 us; speedup 1.0000x reference)
//
#include <hip/hip_runtime.h>

// FP8 MLP, fully fused:  out = q(relu(q(x)@q(w1)^T)) @ q(w2)^T
// R9: BARRIER-FREE fc1 K-loop. Diagnosis: MfmaUtil pinned at ~37% across four
// geometries because block-wide barriers inside the K-step serialize the
// all-waves-LDS phase and all-waves-MFMA phase. Fix: x-panel persistent in LDS
// (quantized in-block, read-only => no anti-deps), w1 fragments loaded direct
// global->reg from an L2-resident blocked layout [nch][ks][256][64B]. The only
// block syncs are 2 barriers/chunk for the H handoff (32 total, was 416).
// Wave tile 64dh x 64batch: 4 dwordx4 (w1) + 4 ds_read_b128 (x) + 16 MFMA/K-step.

typedef float f32x4 __attribute__((ext_vector_type(4)));
typedef float f32x16 __attribute__((ext_vector_type(16)));

#define DIN 784
#define KP  832          // 13 * 64 (zero-padded K)
#define DH  4096
#define NKS 13
#define NCH 16
#define CHUNK 256
#define MROWS 128

__device__ __forceinline__ unsigned long long q8(float4 a, float4 b) {
  int lo = __builtin_amdgcn_cvt_pk_fp8_f32(a.x, a.y, 0, false);
  lo     = __builtin_amdgcn_cvt_pk_fp8_f32(a.z, a.w, lo, true);
  int hi = __builtin_amdgcn_cvt_pk_fp8_f32(b.x, b.y, 0, false);
  hi     = __builtin_amdgcn_cvt_pk_fp8_f32(b.z, b.w, hi, true);
  return (unsigned long long)(unsigned)lo |
         ((unsigned long long)(unsigned)hi << 32);
}

// ---- w1 quantize: f32 [4096][784] -> fp8 blocked [nch16][ks13][256][64B] ----
// 64B k-block content (verified R4-R8 convention): group q (16B) holds
// va = q(w1[n][ks*64 + (q&1)*32 + (q>>1)*8 .. +8]) and vb = same +16.

__global__ __launch_bounds__(256) void quant_w1_k(const float* __restrict__ w1,
                                                  unsigned char* __restrict__ w1qb) {
  int idx = blockIdx.x * 256 + threadIdx.x;       // 4096 n * 52 groups
  int n = idx / 52, g = idx % 52;
  int ks = g >> 2, q = g & 3;
  int kA = ks * 64 + (q & 1) * 32 + (q >> 1) * 8;
  int kB = kA + 16;
  const float* r = w1 + (size_t)n * DIN;
  unsigned long long va = 0ull, vb = 0ull;
  if (kA < DIN) va = q8(*(const float4*)(r + kA), *(const float4*)(r + kA + 4));
  if (kB < DIN) vb = q8(*(const float4*)(r + kB), *(const float4*)(r + kB + 4));
  ulonglong2 v; v.x = va; v.y = vb;
  size_t off = ((size_t)((n >> 8) * NKS + ks) * 256 + (n & 255)) * 64 + q * 16;
  *(ulonglong2*)(w1qb + off) = v;
}

__global__ __launch_bounds__(256) void quant_w2_k(const float* __restrict__ w2,
                                                  unsigned char* __restrict__ w2q) {
  int idx = blockIdx.x * 256 + threadIdx.x;       // 16 rows * 256 chunks(16B)
  int r = idx >> 8, c = idx & 255;
  ulonglong2 v; v.x = 0ull; v.y = 0ull;
  if (r < 10) {
    const float* p = w2 + (size_t)r * DH + c * 16;
    v.x = q8(*(const float4*)(p), *(const float4*)(p + 4));
    v.y = q8(*(const float4*)(p + 8), *(const float4*)(p + 12));
  }
  *(ulonglong2*)(w2q + (size_t)r * DH + c * 16) = v;  // rows 10..15 = 0
}

// ------------------------------ fused MLP -----------------------------------

__global__ __launch_bounds__(512, 2)
void fused_mlp(const float* __restrict__ x,
               const unsigned char* __restrict__ w1qb,
               const unsigned char* __restrict__ w2q,
               float* __restrict__ out) {
  __shared__ unsigned char A[NKS * MROWS * 64];   // 104 KB, x-panel, read-only
  __shared__ unsigned char H[MROWS * CHUNK];      // 32 KB

  const int tid = threadIdx.x;
  const int lane = tid & 63;
  const int w  = tid >> 6;          // wave 0..7
  const int l31 = lane & 31;
  const int hi  = lane >> 5;
  const int wdi = w >> 1;           // dh 64-slice (0..3)
  const int wbi = w & 1;            // batch 64-half
  const long row0 = (long)blockIdx.x * MROWS;

  // ---- prologue: quantize 128 x-rows into the LDS panel (k-interleaved +
  //      slot involution q ^ ((row>>1)&3); same content convention as w1) ----
  for (int it = 0; it < 13; ++it) {
    int idx = tid + it * 512;                     // 13*128*4 = 6656 exactly
    int ks = idx >> 9, rem = idx & 511, row = rem >> 2, q = rem & 3;
    int kA = ks * 64 + (q & 1) * 32 + (q >> 1) * 8;
    int kB = kA + 16;
    const float* xr = x + (row0 + row) * DIN;
    unsigned long long va = 0ull, vb = 0ull;
    if (kA < DIN) va = q8(*(const float4*)(xr + kA), *(const float4*)(xr + kA + 4));
    if (kB < DIN) vb = q8(*(const float4*)(xr + kB), *(const float4*)(xr + kB + 4));
    ulonglong2 v; v.x = va; v.y = vb;
    int slot = q ^ ((row >> 1) & 3);
    *(ulonglong2*)&A[ks * 8192 + row * 64 + slot * 16] = v;
  }
  __syncthreads();   // panel ready; the ONLY full sync before the chunk loop

  // loop-invariant offsets
  const int aoff0 = (wdi * 64 + l31) * 64 + hi * 32;        // w1 row frag ai=0
  const int aoff1 = aoff0 + 32 * 64;                        // ai=1
  const int br0 = wbi * 64 + l31, br1 = br0 + 32;           // x batch rows
#define SOFF(r_, g_) ((r_) * 64 + ((((g_) ^ (((r_) >> 1) & 3))) << 4))
  const int xlo0 = SOFF(br0, 2 * hi), xhi0 = SOFF(br0, 2 * hi + 1);
  const int xlo1 = SOFF(br1, 2 * hi), xhi1 = SOFF(br1, 2 * hi + 1);
#undef SOFF
  const int r2 = w * 16 + (lane & 15);                      // fc2 batch row
  const int x2 = (lane & 15) << 1;
  const int dh0 = wdi * 64 + 4 * hi;                        // H-write dh bases
  const int dh1 = dh0 + 32;

  f32x4 acc2 = {0.f, 0.f, 0.f, 0.f};
  for (int nch = 0; nch < NCH; ++nch) {
    f32x16 a00 = {}, a01 = {}, a10 = {}, a11 = {};
    const unsigned char* wb = w1qb + ((size_t)(nch * NKS) << 14);
#pragma unroll
    for (int ks = 0; ks < NKS; ++ks) {
      const unsigned char* ab = wb + ((size_t)ks << 14);
      // w1 fragments: 4 coalesced dwordx4 from global (L2-resident)
      ulonglong2 A0lo = *(const ulonglong2*)(ab + aoff0);
      ulonglong2 A0hi = *(const ulonglong2*)(ab + aoff0 + 16);
      ulonglong2 A1lo = *(const ulonglong2*)(ab + aoff1);
      ulonglong2 A1hi = *(const ulonglong2*)(ab + aoff1 + 16);
      // x fragments: 4 b128 from the read-only LDS panel
      ulonglong2 B0lo = *(const ulonglong2*)&A[ks * 8192 + xlo0];
      ulonglong2 B0hi = *(const ulonglong2*)&A[ks * 8192 + xhi0];
      ulonglong2 B1lo = *(const ulonglong2*)&A[ks * 8192 + xlo1];
      ulonglong2 B1hi = *(const ulonglong2*)&A[ks * 8192 + xhi1];
      __builtin_amdgcn_s_setprio(1);
      // kslice 0 (lo.x), 1 (lo.y), 2 (hi.x), 3 (hi.y)
      a00 = __builtin_amdgcn_mfma_f32_32x32x16_fp8_fp8((long)A0lo.x, (long)B0lo.x, a00, 0, 0, 0);
      a01 = __builtin_amdgcn_mfma_f32_32x32x16_fp8_fp8((long)A0lo.x, (long)B1lo.x, a01, 0, 0, 0);
      a10 = __builtin_amdgcn_mfma_f32_32x32x16_fp8_fp8((long)A1lo.x, (long)B0lo.x, a10, 0, 0, 0);
      a11 = __builtin_amdgcn_mfma_f32_32x32x16_fp8_fp8((long)A1lo.x, (long)B1lo.x, a11, 0, 0, 0);
      a00 = __builtin_amdgcn_mfma_f32_32x32x16_fp8_fp8((long)A0lo.y, (long)B0lo.y, a00, 0, 0, 0);
      a01 = __builtin_amdgcn_mfma_f32_32x32x16_fp8_fp8((long)A0lo.y, (long)B1lo.y, a01, 0, 0, 0);
      a10 = __builtin_amdgcn_mfma_f32_32x32x16_fp8_fp8((long)A1lo.y, (long)B0lo.y, a10, 0, 0, 0);
      a11 = __builtin_amdgcn_mfma_f32_32x32x16_fp8_fp8((long)A1lo.y, (long)B1lo.y, a11, 0, 0, 0);
      a00 = __builtin_amdgcn_mfma_f32_32x32x16_fp8_fp8((long)A0hi.x, (long)B0hi.x, a00, 0, 0, 0);
      a01 = __builtin_amdgcn_mfma_f32_32x32x16_fp8_fp8((long)A0hi.x, (long)B1hi.x, a01, 0, 0, 0);
      a10 = __builtin_amdgcn_mfma_f32_32x32x16_fp8_fp8((long)A1hi.x, (long)B0hi.x, a10, 0, 0, 0);
      a11 = __builtin_amdgcn_mfma_f32_32x32x16_fp8_fp8((long)A1hi.x, (long)B1hi.x, a11, 0, 0, 0);
      a00 = __builtin_amdgcn_mfma_f32_32x32x16_fp8_fp8((long)A0hi.y, (long)B0hi.y, a00, 0, 0, 0);
      a01 = __builtin_amdgcn_mfma_f32_32x32x16_fp8_fp8((long)A0hi.y, (long)B1hi.y, a01, 0, 0, 0);
      a10 = __builtin_amdgcn_mfma_f32_32x32x16_fp8_fp8((long)A1hi.y, (long)B0hi.y, a10, 0, 0, 0);
      a11 = __builtin_amdgcn_mfma_f32_32x32x16_fp8_fp8((long)A1hi.y, (long)B1hi.y, a11, 0, 0, 0);
      __builtin_amdgcn_s_setprio(0);
    }

    // ---- relu + quantize -> H (dh-in-frag = (reg&3) + 8*(reg>>2) + 4*hi) ----
#define HWR(accv, rbv, dhb)                                                    \
    do {                                                                       \
      _Pragma("unroll") for (int qq = 0; qq < 4; ++qq) {                       \
        int dh_ = (dhb) + 8 * qq;                                              \
        unsigned wv = (unsigned)__builtin_amdgcn_cvt_pk_fp8_f32(               \
            fmaxf((accv)[4*qq+0], 0.f), fmaxf((accv)[4*qq+1], 0.f), 0, false); \
        wv = (unsigned)__builtin_amdgcn_cvt_pk_fp8_f32(                        \
            fmaxf((accv)[4*qq+2], 0.f), fmaxf((accv)[4*qq+3], 0.f), (int)wv, true); \
        int sp_ = (dh_ >> 2) ^ (((rbv) & 15) << 1);                            \
        *(unsigned int*)&H[(rbv) * CHUNK + sp_ * 4] = wv;                      \
      }                                                                        \
    } while (0)
    HWR(a00, br0, dh0);
    HWR(a01, br1, dh0);
    HWR(a10, br0, dh1);
    HWR(a11, br1, dh1);
#undef HWR
    asm volatile("s_waitcnt lgkmcnt(0)" ::: "memory");
    __builtin_amdgcn_s_barrier();
    asm volatile("" ::: "memory");

    // ---- fc2: 8 MFMAs (16x16x32), wave w -> rows w*16..w*16+15 ----
    {
      const unsigned char* w2p = w2q + (size_t)(lane & 15) * DH + nch * CHUNK;
#pragma unroll
      for (int kk = 0; kk < 8; ++kk) {
        int dhl = kk * 32 + (lane >> 4) * 8;
        long a2 = *(const long long*)&H[r2 * CHUNK + ((((dhl >> 2) ^ x2)) << 2)];
        long b2 = *(const long long*)(w2p + dhl);
        acc2 = __builtin_amdgcn_mfma_f32_16x16x32_fp8_fp8(a2, b2, acc2, 0, 0, 0);
      }
    }
    asm volatile("s_waitcnt lgkmcnt(0)" ::: "memory");
    __builtin_amdgcn_s_barrier();   // H reads done before next chunk's writes
    asm volatile("" ::: "memory");
  }

  // ---- store out[128][10]: wave w rows w*16.., col = lane&15 ----
  if ((lane & 15) < 10) {
#pragma unroll
    for (int j = 0; j < 4; ++j) {
      int rl = w * 16 + (lane >> 4) * 4 + j;
      out[(row0 + rl) * 10 + (lane & 15)] = acc2[j];
    }
  }
}

extern "C" void kernel_launch(void* const* d_in, const int* in_sizes, int n_in,
                              void* d_out, int out_size, void* d_ws, size_t ws_size,
                              hipStream_t stream) {
  const float* x  = (const float*)d_in[0];
  const float* w1 = (const float*)d_in[1];
  const float* w2 = (const float*)d_in[2];
  float* out = (float*)d_out;

  unsigned char* w1qb = (unsigned char*)d_ws;             // blocked [16][13][256][64]
  unsigned char* w2q  = w1qb + (size_t)DH * KP;           // [16][4096]

  quant_w1_k<<<(DH * 52) / 256, 256, 0, stream>>>(w1, w1qb);
  quant_w2_k<<<16, 256, 0, stream>>>(w2, w2q);
  fused_mlp<<<256, 512, 0, stream>>>(x, w1qb, w2q, out);
}

// Round 10
// 194.917 us; speedup vs baseline: 2.4702x; 2.4702x over previous
//
#include <hip/hip_runtime.h>

// FP8 MLP, fully fused:  out = q(relu(q(x)@q(w1)^T)) @ q(w2)^T
// R10: barrier-free fc1 K-loop (R9 architecture) with R9's two bugs fixed:
//  (1) w1 blocked layout is WAVE-COALESCED: per (ks, dh-slice), four 1KB
//      sub-blocks [t*2+ai][lane*16] -> each wave-load is 1KB contiguous,
//      one base register + immediate offsets 1024/2048/3072.
//  (2) register double-buffer with #pragma unroll 2 (static [t&1] indices,
//      rule-#20 pattern) instead of full unroll -> no spills.
// x-panel persistent in LDS (quantized in-block, read-only). 2 barriers per
// chunk (H handoff) only. Per-K-step/CU: MFMA 1178 cyc (floor), L2 585, LDS 384.

typedef float f32x4 __attribute__((ext_vector_type(4)));
typedef float f32x16 __attribute__((ext_vector_type(16)));

#define DIN 784
#define KP  832          // 13 * 64 (zero-padded K)
#define DH  4096
#define NKS 13
#define NCH 16
#define CHUNK 256
#define MROWS 128

__device__ __forceinline__ unsigned long long q8(float4 a, float4 b) {
  int lo = __builtin_amdgcn_cvt_pk_fp8_f32(a.x, a.y, 0, false);
  lo     = __builtin_amdgcn_cvt_pk_fp8_f32(a.z, a.w, lo, true);
  int hi = __builtin_amdgcn_cvt_pk_fp8_f32(b.x, b.y, 0, false);
  hi     = __builtin_amdgcn_cvt_pk_fp8_f32(b.z, b.w, hi, true);
  return (unsigned long long)(unsigned)lo |
         ((unsigned long long)(unsigned)hi << 32);
}

__device__ __forceinline__ f32x16 zero16() { f32x16 z = {}; return z; }

// ---- w1 quantize: f32 [4096][784] -> fp8, wave-coalesced blocked layout ----
// Block (nch*13+ks) is 16KB at ((n>>8)*13+ks)<<14. Within: slice=(n>>6)&3 (4KB),
// sub-block (t*2+ai) (1KB, t=chunk-half, ai=row-32-group), lane=(hi*32+l31)*16.
// 16B content (R4..R9 convention): q=2*hi+t -> va=q8(w1[n][ks*64+(q&1)*32+(q>>1)*8..]),
// vb = same +16.

__global__ __launch_bounds__(256) void quant_w1_k(const float* __restrict__ w1,
                                                  unsigned char* __restrict__ w1qb) {
  int idx = blockIdx.x * 256 + threadIdx.x;       // 4096 n * 52 groups
  int n = idx / 52, g = idx % 52;
  int ks = g >> 2, q = g & 3;
  int kA = ks * 64 + (q & 1) * 32 + (q >> 1) * 8;
  int kB = kA + 16;
  const float* r = w1 + (size_t)n * DIN;
  unsigned long long va = 0ull, vb = 0ull;
  if (kA < DIN) va = q8(*(const float4*)(r + kA), *(const float4*)(r + kA + 4));
  if (kB < DIN) vb = q8(*(const float4*)(r + kB), *(const float4*)(r + kB + 4));
  ulonglong2 v; v.x = va; v.y = vb;
  int slice = (n >> 6) & 3, rr = n & 63, ai = rr >> 5, l31n = rr & 31;
  int hi2 = q >> 1, tq = q & 1;
  size_t off = ((size_t)((n >> 8) * NKS + ks) << 14) + slice * 4096 +
               (tq * 2 + ai) * 1024 + (hi2 * 32 + l31n) * 16;
  *(ulonglong2*)(w1qb + off) = v;
}

__global__ __launch_bounds__(256) void quant_w2_k(const float* __restrict__ w2,
                                                  unsigned char* __restrict__ w2q) {
  int idx = blockIdx.x * 256 + threadIdx.x;       // 16 rows * 256 chunks(16B)
  int r = idx >> 8, c = idx & 255;
  ulonglong2 v; v.x = 0ull; v.y = 0ull;
  if (r < 10) {
    const float* p = w2 + (size_t)r * DH + c * 16;
    v.x = q8(*(const float4*)(p), *(const float4*)(p + 4));
    v.y = q8(*(const float4*)(p + 8), *(const float4*)(p + 12));
  }
  *(ulonglong2*)(w2q + (size_t)r * DH + c * 16) = v;  // rows 10..15 = 0
}

// ------------------------------ fused MLP -----------------------------------

__global__ __launch_bounds__(512, 1)
void fused_mlp(const float* __restrict__ x,
               const unsigned char* __restrict__ w1qb,
               const unsigned char* __restrict__ w2q,
               float* __restrict__ out) {
  __shared__ unsigned char A[NKS * MROWS * 64];   // 104 KB x-panel, read-only
  __shared__ unsigned char H[MROWS * CHUNK];      // 32 KB

  const int tid = threadIdx.x;
  const int lane = tid & 63;
  const int w  = tid >> 6;          // wave 0..7
  const int l31 = lane & 31;
  const int hi  = lane >> 5;
  const int wdi = w >> 1;           // dh 64-slice (0..3)
  const int wbi = w & 1;            // batch 64-half
  const long row0 = (long)blockIdx.x * MROWS;

  // ---- prologue: quantize 128 x-rows into the LDS panel ----
  for (int it = 0; it < 13; ++it) {
    int idx = tid + it * 512;                     // 13*128*4 = 6656 exactly
    int ks = idx >> 9, rem = idx & 511, row = rem >> 2, q = rem & 3;
    int kA = ks * 64 + (q & 1) * 32 + (q >> 1) * 8;
    int kB = kA + 16;
    const float* xr = x + (row0 + row) * DIN;
    unsigned long long va = 0ull, vb = 0ull;
    if (kA < DIN) va = q8(*(const float4*)(xr + kA), *(const float4*)(xr + kA + 4));
    if (kB < DIN) vb = q8(*(const float4*)(xr + kB), *(const float4*)(xr + kB + 4));
    ulonglong2 v; v.x = va; v.y = vb;
    int slot = q ^ ((row >> 1) & 3);
    *(ulonglong2*)&A[ks * 8192 + row * 64 + slot * 16] = v;
  }
  __syncthreads();   // panel ready

  // loop-invariant offsets
  const int br0 = wbi * 64 + l31, br1 = br0 + 32;           // x batch rows
#define SOFF(r_, g_) ((r_) * 64 + ((((g_) ^ (((r_) >> 1) & 3))) << 4))
  const int xlo0 = SOFF(br0, 2 * hi), xhi0 = SOFF(br0, 2 * hi + 1);
  const int xlo1 = SOFF(br1, 2 * hi), xhi1 = SOFF(br1, 2 * hi + 1);
#undef SOFF
  const int r2 = w * 16 + (lane & 15);                      // fc2 batch row
  const int x2 = (lane & 15) << 1;
  const int dh0 = wdi * 64 + 4 * hi;                        // H-write dh bases
  const int dh1 = dh0 + 32;
  const unsigned char* w2base = w2q + (size_t)(lane & 15) * DH;
  const unsigned char* wbase = w1qb + wdi * 4096 + (size_t)lane * 16;

  ulonglong2 wb_[2][4];
  {
    const unsigned char* p0 = wbase;              // t = 0
    wb_[0][0] = *(const ulonglong2*)(p0);
    wb_[0][1] = *(const ulonglong2*)(p0 + 1024);
    wb_[0][2] = *(const ulonglong2*)(p0 + 2048);
    wb_[0][3] = *(const ulonglong2*)(p0 + 3072);
  }

  f32x16 a00 = zero16(), a01 = zero16(), a10 = zero16(), a11 = zero16();
  f32x4 acc2 = {0.f, 0.f, 0.f, 0.f};
  int ks = 0;
  int w2col = 0;

#pragma unroll 2
  for (int t = 0; t < NCH * NKS; ++t) {
    const int cur = t & 1;
    // prefetch next tile's w1 fragments (coalesced 4x1KB; in flight under MFMAs)
    if (t + 1 < NCH * NKS) {
      const unsigned char* np = wbase + ((size_t)(t + 1) << 14);
      wb_[cur ^ 1][0] = *(const ulonglong2*)(np);
      wb_[cur ^ 1][1] = *(const ulonglong2*)(np + 1024);
      wb_[cur ^ 1][2] = *(const ulonglong2*)(np + 2048);
      wb_[cur ^ 1][3] = *(const ulonglong2*)(np + 3072);
    }
    // x fragments from the read-only panel
    const unsigned char* Ab = &A[ks * 8192];
    ulonglong2 B0lo = *(const ulonglong2*)(Ab + xlo0);
    ulonglong2 B0hi = *(const ulonglong2*)(Ab + xhi0);
    ulonglong2 B1lo = *(const ulonglong2*)(Ab + xlo1);
    ulonglong2 B1hi = *(const ulonglong2*)(Ab + xhi1);

    const ulonglong2 A0lo = wb_[cur][0];   // (t=0, ai=0)
    const ulonglong2 A1lo = wb_[cur][1];   // (t=0, ai=1)
    const ulonglong2 A0hi = wb_[cur][2];   // (t=1, ai=0)
    const ulonglong2 A1hi = wb_[cur][3];   // (t=1, ai=1)

    __builtin_amdgcn_s_setprio(1);
    a00 = __builtin_amdgcn_mfma_f32_32x32x16_fp8_fp8((long)A0lo.x, (long)B0lo.x, a00, 0, 0, 0);
    a01 = __builtin_amdgcn_mfma_f32_32x32x16_fp8_fp8((long)A0lo.x, (long)B1lo.x, a01, 0, 0, 0);
    a10 = __builtin_amdgcn_mfma_f32_32x32x16_fp8_fp8((long)A1lo.x, (long)B0lo.x, a10, 0, 0, 0);
    a11 = __builtin_amdgcn_mfma_f32_32x32x16_fp8_fp8((long)A1lo.x, (long)B1lo.x, a11, 0, 0, 0);
    a00 = __builtin_amdgcn_mfma_f32_32x32x16_fp8_fp8((long)A0lo.y, (long)B0lo.y, a00, 0, 0, 0);
    a01 = __builtin_amdgcn_mfma_f32_32x32x16_fp8_fp8((long)A0lo.y, (long)B1lo.y, a01, 0, 0, 0);
    a10 = __builtin_amdgcn_mfma_f32_32x32x16_fp8_fp8((long)A1lo.y, (long)B0lo.y, a10, 0, 0, 0);
    a11 = __builtin_amdgcn_mfma_f32_32x32x16_fp8_fp8((long)A1lo.y, (long)B1lo.y, a11, 0, 0, 0);
    a00 = __builtin_amdgcn_mfma_f32_32x32x16_fp8_fp8((long)A0hi.x, (long)B0hi.x, a00, 0, 0, 0);
    a01 = __builtin_amdgcn_mfma_f32_32x32x16_fp8_fp8((long)A0hi.x, (long)B1hi.x, a01, 0, 0, 0);
    a10 = __builtin_amdgcn_mfma_f32_32x32x16_fp8_fp8((long)A1hi.x, (long)B0hi.x, a10, 0, 0, 0);
    a11 = __builtin_amdgcn_mfma_f32_32x32x16_fp8_fp8((long)A1hi.x, (long)B1hi.x, a11, 0, 0, 0);
    a00 = __builtin_amdgcn_mfma_f32_32x32x16_fp8_fp8((long)A0hi.y, (long)B0hi.y, a00, 0, 0, 0);
    a01 = __builtin_amdgcn_mfma_f32_32x32x16_fp8_fp8((long)A0hi.y, (long)B1hi.y, a01, 0, 0, 0);
    a10 = __builtin_amdgcn_mfma_f32_32x32x16_fp8_fp8((long)A1hi.y, (long)B0hi.y, a10, 0, 0, 0);
    a11 = __builtin_amdgcn_mfma_f32_32x32x16_fp8_fp8((long)A1hi.y, (long)B1hi.y, a11, 0, 0, 0);
    __builtin_amdgcn_s_setprio(0);

    if (ks == NKS - 1) {
      // ---- relu + quantize -> H (dh-in-frag = (reg&3) + 8*(reg>>2) + 4*hi) ----
#define HWR(accv, rbv, dhb)                                                    \
      do {                                                                     \
        _Pragma("unroll") for (int qq = 0; qq < 4; ++qq) {                     \
          int dh_ = (dhb) + 8 * qq;                                            \
          unsigned wv = (unsigned)__builtin_amdgcn_cvt_pk_fp8_f32(             \
              fmaxf((accv)[4*qq+0], 0.f), fmaxf((accv)[4*qq+1], 0.f), 0, false); \
          wv = (unsigned)__builtin_amdgcn_cvt_pk_fp8_f32(                      \
              fmaxf((accv)[4*qq+2], 0.f), fmaxf((accv)[4*qq+3], 0.f), (int)wv, true); \
          int sp_ = (dh_ >> 2) ^ (((rbv) & 15) << 1);                          \
          *(unsigned int*)&H[(rbv) * CHUNK + sp_ * 4] = wv;                    \
        }                                                                      \
      } while (0)
      HWR(a00, br0, dh0);
      HWR(a01, br1, dh0);
      HWR(a10, br0, dh1);
      HWR(a11, br1, dh1);
#undef HWR
      a00 = zero16(); a01 = zero16(); a10 = zero16(); a11 = zero16();
      asm volatile("s_waitcnt lgkmcnt(0)" ::: "memory");
      __builtin_amdgcn_s_barrier();
      asm volatile("" ::: "memory");
      // ---- fc2: 8 MFMAs (16x16x32), wave w -> rows w*16..w*16+15 ----
      {
        const unsigned char* w2p = w2base + w2col;
#pragma unroll
        for (int kk = 0; kk < 8; ++kk) {
          int dhl = kk * 32 + (lane >> 4) * 8;
          long a2 = *(const long long*)&H[r2 * CHUNK + ((((dhl >> 2) ^ x2)) << 2)];
          long b2 = *(const long long*)(w2p + dhl);
          acc2 = __builtin_amdgcn_mfma_f32_16x16x32_fp8_fp8(a2, b2, acc2, 0, 0, 0);
        }
      }
      asm volatile("s_waitcnt lgkmcnt(0)" ::: "memory");
      __builtin_amdgcn_s_barrier();   // H reads done before next chunk's writes
      asm volatile("" ::: "memory");
      w2col += CHUNK;
      ks = 0;
    } else {
      ++ks;
    }
  }

  // ---- store out[128][10]: wave w rows w*16.., col = lane&15 ----
  if ((lane & 15) < 10) {
#pragma unroll
    for (int j = 0; j < 4; ++j) {
      int rl = w * 16 + (lane >> 4) * 4 + j;
      out[(row0 + rl) * 10 + (lane & 15)] = acc2[j];
    }
  }
}

extern "C" void kernel_launch(void* const* d_in, const int* in_sizes, int n_in,
                              void* d_out, int out_size, void* d_ws, size_t ws_size,
                              hipStream_t stream) {
  const float* x  = (const float*)d_in[0];
  const float* w1 = (const float*)d_in[1];
  const float* w2 = (const float*)d_in[2];
  float* out = (float*)d_out;

  unsigned char* w1qb = (unsigned char*)d_ws;             // blocked, 3.4MB
  unsigned char* w2q  = w1qb + (size_t)DH * KP;           // [16][4096]

  quant_w1_k<<<(DH * 52) / 256, 256, 0, stream>>>(w1, w1qb);
  quant_w2_k<<<16, 256, 0, stream>>>(w2, w2q);
  fused_mlp<<<256, 512, 0, stream>>>(x, w1qb, w2q, out);
}

// Round 11
// 186.960 us; speedup vs baseline: 2.5753x; 1.0426x over previous
//
#include <hip/hip_runtime.h>

// FP8 MLP, fully fused:  out = q(relu(q(x)@q(w1)^T)) @ q(w2)^T
// R11: R10's barrier-free fc1 loop at 2 blocks/CU (4 waves/SIMD).
// M=64 rows/block, grid=512; LDS 68KB (A 52KB + H 16KB) -> 2 blocks co-resident,
// mutually unsynchronized (anti-phase overlap of epilogues with MFMAs).
// Wave tile 32dh x 64batch: 2x1KB coalesced w1 reg-loads (dbuf, unroll 2),
// 4 ds_read_b128, 8 MFMA per K-step. fc2 k-split by wave, end pair-reduce.

typedef float f32x4 __attribute__((ext_vector_type(4)));
typedef float f32x16 __attribute__((ext_vector_type(16)));

#define DIN 784
#define KP  832          // 13 * 64 (zero-padded K)
#define DH  4096
#define NKS 13
#define NCH 16
#define CHUNK 256
#define MROWS 64

__device__ __forceinline__ unsigned long long q8(float4 a, float4 b) {
  int lo = __builtin_amdgcn_cvt_pk_fp8_f32(a.x, a.y, 0, false);
  lo     = __builtin_amdgcn_cvt_pk_fp8_f32(a.z, a.w, lo, true);
  int hi = __builtin_amdgcn_cvt_pk_fp8_f32(b.x, b.y, 0, false);
  hi     = __builtin_amdgcn_cvt_pk_fp8_f32(b.z, b.w, hi, true);
  return (unsigned long long)(unsigned)lo |
         ((unsigned long long)(unsigned)hi << 32);
}

__device__ __forceinline__ f32x16 zero16() { f32x16 z = {}; return z; }

// ---- w1 quantize: f32 [4096][784] -> fp8, wave-coalesced blocked layout ----
// 16KB block (nch*13+ks). Within: slice=(n>>5)&7 (2KB = 32 dh rows),
// tq=q&1 (1KB = k-half 0-31/32-63), lane 16B = ((q>>1)*32 + (n&31))*16.
// 16B content (R4..R10 convention): va=q8(w1[n][ks*64+(q&1)*32+(q>>1)*8..+8]),
// vb = same +16.

__global__ __launch_bounds__(256) void quant_w1_k(const float* __restrict__ w1,
                                                  unsigned char* __restrict__ w1qb) {
  int idx = blockIdx.x * 256 + threadIdx.x;       // 4096 n * 52 groups
  int n = idx / 52, g = idx % 52;
  int ks = g >> 2, q = g & 3;
  int kA = ks * 64 + (q & 1) * 32 + (q >> 1) * 8;
  int kB = kA + 16;
  const float* r = w1 + (size_t)n * DIN;
  unsigned long long va = 0ull, vb = 0ull;
  if (kA < DIN) va = q8(*(const float4*)(r + kA), *(const float4*)(r + kA + 4));
  if (kB < DIN) vb = q8(*(const float4*)(r + kB), *(const float4*)(r + kB + 4));
  ulonglong2 v; v.x = va; v.y = vb;
  size_t off = ((size_t)((n >> 8) * NKS + ks) << 14) + ((n >> 5) & 7) * 2048 +
               (q & 1) * 1024 + ((q >> 1) * 32 + (n & 31)) * 16;
  *(ulonglong2*)(w1qb + off) = v;
}

__global__ __launch_bounds__(256) void quant_w2_k(const float* __restrict__ w2,
                                                  unsigned char* __restrict__ w2q) {
  int idx = blockIdx.x * 256 + threadIdx.x;       // 16 rows * 256 chunks(16B)
  int r = idx >> 8, c = idx & 255;
  ulonglong2 v; v.x = 0ull; v.y = 0ull;
  if (r < 10) {
    const float* p = w2 + (size_t)r * DH + c * 16;
    v.x = q8(*(const float4*)(p), *(const float4*)(p + 4));
    v.y = q8(*(const float4*)(p + 8), *(const float4*)(p + 12));
  }
  *(ulonglong2*)(w2q + (size_t)r * DH + c * 16) = v;  // rows 10..15 = 0
}

// ------------------------------ fused MLP -----------------------------------

__global__ __launch_bounds__(512, 4)
void fused_mlp(const float* __restrict__ x,
               const unsigned char* __restrict__ w1qb,
               const unsigned char* __restrict__ w2q,
               float* __restrict__ out) {
  __shared__ unsigned char A[NKS * MROWS * 64];   // 52 KB x-panel, read-only
  __shared__ unsigned char H[MROWS * CHUNK];      // 16 KB

  const int tid = threadIdx.x;
  const int lane = tid & 63;
  const int w  = tid >> 6;          // wave 0..7 -> dh slice w*32 of the chunk
  const int l31 = lane & 31;
  const int hi  = lane >> 5;
  const long row0 = (long)blockIdx.x * MROWS;

  // ---- prologue: quantize 64 x-rows into the LDS panel ----
  for (int it = 0; it < 7; ++it) {
    int idx = tid + it * 512;                     // 13*64*4 = 3328 writes
    if (idx < NKS * 256) {
      int ks = idx >> 8, rem = idx & 255, row = rem >> 2, q = rem & 3;
      int kA = ks * 64 + (q & 1) * 32 + (q >> 1) * 8;
      int kB = kA + 16;
      const float* xr = x + (row0 + row) * DIN;
      unsigned long long va = 0ull, vb = 0ull;
      if (kA < DIN) va = q8(*(const float4*)(xr + kA), *(const float4*)(xr + kA + 4));
      if (kB < DIN) vb = q8(*(const float4*)(xr + kB), *(const float4*)(xr + kB + 4));
      ulonglong2 v; v.x = va; v.y = vb;
      int slot = q ^ ((row >> 1) & 3);
      *(ulonglong2*)&A[ks * 4096 + row * 64 + slot * 16] = v;
    }
  }
  __syncthreads();   // panel ready

  // loop-invariant offsets
  const int br0 = l31, br1 = l31 + 32;                      // x batch rows
#define SOFF(r_, g_) ((r_) * 64 + ((((g_) ^ (((r_) >> 1) & 3))) << 4))
  const int xlo0 = SOFF(br0, 2 * hi), xhi0 = SOFF(br0, 2 * hi + 1);
  const int xlo1 = SOFF(br1, 2 * hi), xhi1 = SOFF(br1, 2 * hi + 1);
#undef SOFF
  const int wh = w & 3, kh = w >> 2;                        // fc2: row quad, k-half
  const int r2 = wh * 16 + (lane & 15);                     // fc2 batch row
  const int x2 = (lane & 15) << 1;
  const int dh0 = w * 32 + 4 * hi;                          // H-write dh base
  const unsigned char* w2base = w2q + (size_t)(lane & 15) * DH;
  const unsigned char* wbase = w1qb + w * 2048 + (size_t)lane * 16;

  ulonglong2 wb_[2][2];
  wb_[0][0] = *(const ulonglong2*)(wbase);
  wb_[0][1] = *(const ulonglong2*)(wbase + 1024);

  f32x16 c0 = zero16(), c1 = zero16();
  f32x4 acc2 = {0.f, 0.f, 0.f, 0.f};
  int ks = 0;
  int w2col = 0;

#pragma unroll 2
  for (int t = 0; t < NCH * NKS; ++t) {
    const int cur = t & 1;
    // prefetch next tile's w1 fragments (2x1KB coalesced, in flight under MFMAs)
    if (t + 1 < NCH * NKS) {
      const unsigned char* np = wbase + ((size_t)(t + 1) << 14);
      wb_[cur ^ 1][0] = *(const ulonglong2*)(np);
      wb_[cur ^ 1][1] = *(const ulonglong2*)(np + 1024);
    }
    // x fragments from the read-only panel
    const unsigned char* Ab = &A[ks * 4096];
    ulonglong2 B0lo = *(const ulonglong2*)(Ab + xlo0);
    ulonglong2 B0hi = *(const ulonglong2*)(Ab + xhi0);
    ulonglong2 B1lo = *(const ulonglong2*)(Ab + xlo1);
    ulonglong2 B1hi = *(const ulonglong2*)(Ab + xhi1);

    const ulonglong2 Alo = wb_[cur][0];   // k 0..31  (two 16-k slices)
    const ulonglong2 Ahi = wb_[cur][1];   // k 32..63

    __builtin_amdgcn_s_setprio(1);
    c0 = __builtin_amdgcn_mfma_f32_32x32x16_fp8_fp8((long)Alo.x, (long)B0lo.x, c0, 0, 0, 0);
    c1 = __builtin_amdgcn_mfma_f32_32x32x16_fp8_fp8((long)Alo.x, (long)B1lo.x, c1, 0, 0, 0);
    c0 = __builtin_amdgcn_mfma_f32_32x32x16_fp8_fp8((long)Alo.y, (long)B0lo.y, c0, 0, 0, 0);
    c1 = __builtin_amdgcn_mfma_f32_32x32x16_fp8_fp8((long)Alo.y, (long)B1lo.y, c1, 0, 0, 0);
    c0 = __builtin_amdgcn_mfma_f32_32x32x16_fp8_fp8((long)Ahi.x, (long)B0hi.x, c0, 0, 0, 0);
    c1 = __builtin_amdgcn_mfma_f32_32x32x16_fp8_fp8((long)Ahi.x, (long)B1hi.x, c1, 0, 0, 0);
    c0 = __builtin_amdgcn_mfma_f32_32x32x16_fp8_fp8((long)Ahi.y, (long)B0hi.y, c0, 0, 0, 0);
    c1 = __builtin_amdgcn_mfma_f32_32x32x16_fp8_fp8((long)Ahi.y, (long)B1hi.y, c1, 0, 0, 0);
    __builtin_amdgcn_s_setprio(0);

    if (ks == NKS - 1) {
      // ---- relu + quantize -> H (dh-in-frag = (reg&3) + 8*(reg>>2) + 4*hi) ----
#define HWR(accv, rbv, dhb)                                                    \
      do {                                                                     \
        _Pragma("unroll") for (int qq = 0; qq < 4; ++qq) {                     \
          int dh_ = (dhb) + 8 * qq;                                            \
          unsigned wv = (unsigned)__builtin_amdgcn_cvt_pk_fp8_f32(             \
              fmaxf((accv)[4*qq+0], 0.f), fmaxf((accv)[4*qq+1], 0.f), 0, false); \
          wv = (unsigned)__builtin_amdgcn_cvt_pk_fp8_f32(                      \
              fmaxf((accv)[4*qq+2], 0.f), fmaxf((accv)[4*qq+3], 0.f), (int)wv, true); \
          int sp_ = (dh_ >> 2) ^ (((rbv) & 15) << 1);                          \
          *(unsigned int*)&H[(rbv) * CHUNK + sp_ * 4] = wv;                    \
        }                                                                      \
      } while (0)
      HWR(c0, br0, dh0);
      HWR(c1, br1, dh0);
#undef HWR
      c0 = zero16(); c1 = zero16();
      asm volatile("s_waitcnt lgkmcnt(0)" ::: "memory");
      __builtin_amdgcn_s_barrier();
      asm volatile("" ::: "memory");
      // ---- fc2: 4 MFMAs (16x16x32), wave -> rows wh*16.., k-half kh*128 ----
      {
        const unsigned char* w2p = w2base + w2col + kh * 128;
#pragma unroll
        for (int kk = 0; kk < 4; ++kk) {
          int dhl = kk * 32 + (lane >> 4) * 8;
          long a2 = *(const long long*)&H[r2 * CHUNK +
                                          ((((kh * 128 + dhl) >> 2) ^ x2) << 2)];
          long b2 = *(const long long*)(w2p + dhl);
          acc2 = __builtin_amdgcn_mfma_f32_16x16x32_fp8_fp8(a2, b2, acc2, 0, 0, 0);
        }
      }
      asm volatile("s_waitcnt lgkmcnt(0)" ::: "memory");
      __builtin_amdgcn_s_barrier();   // H reads done before next chunk's writes
      asm volatile("" ::: "memory");
      w2col += CHUNK;
      ks = 0;
    } else {
      ++ks;
    }
  }

  // ---- pair-reduce fc2 k-halves (waves wh and wh+4), store out[64][10] ----
  __syncthreads();
  float* red = (float*)&H[0];
  if (kh == 1) {
#pragma unroll
    for (int j = 0; j < 4; ++j)
      red[(wh * 16 + (lane >> 4) * 4 + j) * 16 + (lane & 15)] = acc2[j];
  }
  __syncthreads();
  if (kh == 0 && (lane & 15) < 10) {
#pragma unroll
    for (int j = 0; j < 4; ++j) {
      int rl = wh * 16 + (lane >> 4) * 4 + j;
      out[(row0 + rl) * 10 + (lane & 15)] = acc2[j] + red[rl * 16 + (lane & 15)];
    }
  }
}

extern "C" void kernel_launch(void* const* d_in, const int* in_sizes, int n_in,
                              void* d_out, int out_size, void* d_ws, size_t ws_size,
                              hipStream_t stream) {
  const float* x  = (const float*)d_in[0];
  const float* w1 = (const float*)d_in[1];
  const float* w2 = (const float*)d_in[2];
  float* out = (float*)d_out;

  unsigned char* w1qb = (unsigned char*)d_ws;             // blocked, 3.4MB
  unsigned char* w2q  = w1qb + (size_t)DH * KP;           // [16][4096]

  quant_w1_k<<<(DH * 52) / 256, 256, 0, stream>>>(w1, w1qb);
  quant_w2_k<<<16, 256, 0, stream>>>(w2, w2q);
  fused_mlp<<<32768 / MROWS, 512, 0, stream>>>(x, w1qb, w2q, out);
}

// Round 12
// 172.720 us; speedup vs baseline: 2.7876x; 1.0824x over previous
//
#include <hip/hip_runtime.h>

// FP8 MLP, fully fused:  out = q(relu(q(x)@q(w1)^T)) @ q(w2)^T
// R12: R11 skeleton (M=64, 8 waves, 2 blocks/CU, barrier-free fc1 loop,
// w1 global->reg dbuf) with the issue-tax removed:
//  - two-level loop, inner 13-loop FULLY UNROLLED: ks compile-time, ds_reads
//    via one base VGPR + offset: immediates, static dbuf indices, no branch.
//  - fc2 w2 fragments hoisted to chunk top (13 K-steps of L2 slack).
//  - global prefetch via running pointer + literal adds.

typedef float f32x4 __attribute__((ext_vector_type(4)));
typedef float f32x16 __attribute__((ext_vector_type(16)));

#define DIN 784
#define KP  832          // 13 * 64 (zero-padded K)
#define DH  4096
#define NKS 13
#define NCH 16
#define CHUNK 256
#define MROWS 64

__device__ __forceinline__ unsigned long long q8(float4 a, float4 b) {
  int lo = __builtin_amdgcn_cvt_pk_fp8_f32(a.x, a.y, 0, false);
  lo     = __builtin_amdgcn_cvt_pk_fp8_f32(a.z, a.w, lo, true);
  int hi = __builtin_amdgcn_cvt_pk_fp8_f32(b.x, b.y, 0, false);
  hi     = __builtin_amdgcn_cvt_pk_fp8_f32(b.z, b.w, hi, true);
  return (unsigned long long)(unsigned)lo |
         ((unsigned long long)(unsigned)hi << 32);
}

__device__ __forceinline__ f32x16 zero16() { f32x16 z = {}; return z; }

// ---- w1 quantize: f32 [4096][784] -> fp8, wave-coalesced blocked layout ----
// 16KB block (nch*13+ks). Within: slice=(n>>5)&7 (2KB = 32 dh rows),
// tq=q&1 (1KB = k-half), lane 16B = ((q>>1)*32 + (n&31))*16.
// 16B content: va=q8(w1[n][ks*64+(q&1)*32+(q>>1)*8..+8]), vb = same +16.

__global__ __launch_bounds__(256) void quant_w1_k(const float* __restrict__ w1,
                                                  unsigned char* __restrict__ w1qb) {
  int idx = blockIdx.x * 256 + threadIdx.x;       // 4096 n * 52 groups
  int n = idx / 52, g = idx % 52;
  int ks = g >> 2, q = g & 3;
  int kA = ks * 64 + (q & 1) * 32 + (q >> 1) * 8;
  int kB = kA + 16;
  const float* r = w1 + (size_t)n * DIN;
  unsigned long long va = 0ull, vb = 0ull;
  if (kA < DIN) va = q8(*(const float4*)(r + kA), *(const float4*)(r + kA + 4));
  if (kB < DIN) vb = q8(*(const float4*)(r + kB), *(const float4*)(r + kB + 4));
  ulonglong2 v; v.x = va; v.y = vb;
  size_t off = ((size_t)((n >> 8) * NKS + ks) << 14) + ((n >> 5) & 7) * 2048 +
               (q & 1) * 1024 + ((q >> 1) * 32 + (n & 31)) * 16;
  *(ulonglong2*)(w1qb + off) = v;
}

__global__ __launch_bounds__(256) void quant_w2_k(const float* __restrict__ w2,
                                                  unsigned char* __restrict__ w2q) {
  int idx = blockIdx.x * 256 + threadIdx.x;       // 16 rows * 256 chunks(16B)
  int r = idx >> 8, c = idx & 255;
  ulonglong2 v; v.x = 0ull; v.y = 0ull;
  if (r < 10) {
    const float* p = w2 + (size_t)r * DH + c * 16;
    v.x = q8(*(const float4*)(p), *(const float4*)(p + 4));
    v.y = q8(*(const float4*)(p + 8), *(const float4*)(p + 12));
  }
  *(ulonglong2*)(w2q + (size_t)r * DH + c * 16) = v;  // rows 10..15 = 0
}

// ------------------------------ fused MLP -----------------------------------

__global__ __launch_bounds__(512, 4)
void fused_mlp(const float* __restrict__ x,
               const unsigned char* __restrict__ w1qb,
               const unsigned char* __restrict__ w2q,
               float* __restrict__ out) {
  __shared__ unsigned char A[NKS * MROWS * 64];   // 52 KB x-panel, read-only
  __shared__ unsigned char H[MROWS * CHUNK];      // 16 KB

  const int tid = threadIdx.x;
  const int lane = tid & 63;
  const int w  = tid >> 6;          // wave 0..7 -> dh slice w*32 of the chunk
  const int l31 = lane & 31;
  const int hi  = lane >> 5;
  const long row0 = (long)blockIdx.x * MROWS;

  // ---- prologue: quantize 64 x-rows into the LDS panel ----
  for (int it = 0; it < 7; ++it) {
    int idx = tid + it * 512;                     // 13*64*4 = 3328 writes
    if (idx < NKS * 256) {
      int ks = idx >> 8, rem = idx & 255, row = rem >> 2, q = rem & 3;
      int kA = ks * 64 + (q & 1) * 32 + (q >> 1) * 8;
      int kB = kA + 16;
      const float* xr = x + (row0 + row) * DIN;
      unsigned long long va = 0ull, vb = 0ull;
      if (kA < DIN) va = q8(*(const float4*)(xr + kA), *(const float4*)(xr + kA + 4));
      if (kB < DIN) vb = q8(*(const float4*)(xr + kB), *(const float4*)(xr + kB + 4));
      ulonglong2 v; v.x = va; v.y = vb;
      int slot = q ^ ((row >> 1) & 3);
      *(ulonglong2*)&A[ks * 4096 + row * 64 + slot * 16] = v;
    }
  }
  __syncthreads();   // panel ready

  // loop-invariant offsets
  const int br0 = l31, br1 = l31 + 32;                      // x batch rows
#define SOFF(r_, g_) ((r_) * 64 + ((((g_) ^ (((r_) >> 1) & 3))) << 4))
  const unsigned char* aXlo0 = &A[SOFF(br0, 2 * hi)];
  const unsigned char* aXhi0 = &A[SOFF(br0, 2 * hi + 1)];
  const unsigned char* aXlo1 = &A[SOFF(br1, 2 * hi)];
  const unsigned char* aXhi1 = &A[SOFF(br1, 2 * hi + 1)];
#undef SOFF
  const int wh = w & 3, kh = w >> 2;                        // fc2: row quad, k-half
  const int r2 = wh * 16 + (lane & 15);                     // fc2 batch row
  const int x2 = (lane & 15) << 1;
  const int dh0 = w * 32 + 4 * hi;                          // H-write dh base
  const unsigned char* w2p0 = w2q + (size_t)(lane & 15) * DH + kh * 128 +
                              (lane >> 4) * 8;
  const unsigned char* wptr = w1qb + w * 2048 + (size_t)lane * 16;

  ulonglong2 wb_[2];
  ulonglong2 wbn_[2];
  wb_[0] = *(const ulonglong2*)(wptr);
  wb_[1] = *(const ulonglong2*)(wptr + 1024);

  f32x4 acc2 = {0.f, 0.f, 0.f, 0.f};

#pragma unroll 1
  for (int nch = 0; nch < NCH; ++nch) {
    // hoist fc2 w2 fragments for this chunk (consumed after the inner loop)
    long b2v[4];
#pragma unroll
    for (int kk = 0; kk < 4; ++kk)
      b2v[kk] = *(const long long*)(w2p0 + nch * CHUNK + kk * 32);

    f32x16 c0 = zero16(), c1 = zero16();
#pragma unroll
    for (int ks = 0; ks < NKS; ++ks) {
      // prefetch tile ks+1 (next chunk's tile 0 when ks==12)
      if (ks < NKS - 1 || nch < NCH - 1) {
        const unsigned char* np = wptr + (size_t)((ks + 1) << 14);
        wbn_[0] = *(const ulonglong2*)(np);
        wbn_[1] = *(const ulonglong2*)(np + 1024);
      }
      // x fragments: immediate-offset ds_reads off 4 base VGPRs
      ulonglong2 B0lo = *(const ulonglong2*)(aXlo0 + ks * 4096);
      ulonglong2 B0hi = *(const ulonglong2*)(aXhi0 + ks * 4096);
      ulonglong2 B1lo = *(const ulonglong2*)(aXlo1 + ks * 4096);
      ulonglong2 B1hi = *(const ulonglong2*)(aXhi1 + ks * 4096);

      const ulonglong2 Alo = wb_[0];   // k 0..31
      const ulonglong2 Ahi = wb_[1];   // k 32..63

      __builtin_amdgcn_s_setprio(1);
      c0 = __builtin_amdgcn_mfma_f32_32x32x16_fp8_fp8((long)Alo.x, (long)B0lo.x, c0, 0, 0, 0);
      c1 = __builtin_amdgcn_mfma_f32_32x32x16_fp8_fp8((long)Alo.x, (long)B1lo.x, c1, 0, 0, 0);
      c0 = __builtin_amdgcn_mfma_f32_32x32x16_fp8_fp8((long)Alo.y, (long)B0lo.y, c0, 0, 0, 0);
      c1 = __builtin_amdgcn_mfma_f32_32x32x16_fp8_fp8((long)Alo.y, (long)B1lo.y, c1, 0, 0, 0);
      c0 = __builtin_amdgcn_mfma_f32_32x32x16_fp8_fp8((long)Ahi.x, (long)B0hi.x, c0, 0, 0, 0);
      c1 = __builtin_amdgcn_mfma_f32_32x32x16_fp8_fp8((long)Ahi.x, (long)B1hi.x, c1, 0, 0, 0);
      c0 = __builtin_amdgcn_mfma_f32_32x32x16_fp8_fp8((long)Ahi.y, (long)B0hi.y, c0, 0, 0, 0);
      c1 = __builtin_amdgcn_mfma_f32_32x32x16_fp8_fp8((long)Ahi.y, (long)B1hi.y, c1, 0, 0, 0);
      __builtin_amdgcn_s_setprio(0);

      wb_[0] = wbn_[0];
      wb_[1] = wbn_[1];
    }
    wptr += (size_t)NKS << 14;

    // ---- relu + quantize -> H (dh-in-frag = (reg&3) + 8*(reg>>2) + 4*hi) ----
#define HWR(accv, rbv, dhb)                                                    \
    do {                                                                       \
      _Pragma("unroll") for (int qq = 0; qq < 4; ++qq) {                       \
        int dh_ = (dhb) + 8 * qq;                                              \
        unsigned wv = (unsigned)__builtin_amdgcn_cvt_pk_fp8_f32(               \
            fmaxf((accv)[4*qq+0], 0.f), fmaxf((accv)[4*qq+1], 0.f), 0, false); \
        wv = (unsigned)__builtin_amdgcn_cvt_pk_fp8_f32(                        \
            fmaxf((accv)[4*qq+2], 0.f), fmaxf((accv)[4*qq+3], 0.f), (int)wv, true); \
        int sp_ = (dh_ >> 2) ^ (((rbv) & 15) << 1);                            \
        *(unsigned int*)&H[(rbv) * CHUNK + sp_ * 4] = wv;                      \
      }                                                                        \
    } while (0)
    HWR(c0, br0, dh0);
    HWR(c1, br1, dh0);
#undef HWR
    asm volatile("s_waitcnt lgkmcnt(0)" ::: "memory");
    __builtin_amdgcn_s_barrier();
    asm volatile("" ::: "memory");
    // ---- fc2: 4 MFMAs (16x16x32), wave -> rows wh*16.., k-half kh*128 ----
#pragma unroll
    for (int kk = 0; kk < 4; ++kk) {
      int dhl = kh * 128 + kk * 32 + (lane >> 4) * 8;
      long a2 = *(const long long*)&H[r2 * CHUNK + (((dhl >> 2) ^ x2) << 2)];
      acc2 = __builtin_amdgcn_mfma_f32_16x16x32_fp8_fp8(a2, b2v[kk], acc2, 0, 0, 0);
    }
    asm volatile("s_waitcnt lgkmcnt(0)" ::: "memory");
    __builtin_amdgcn_s_barrier();   // H reads done before next chunk's writes
    asm volatile("" ::: "memory");
  }

  // ---- pair-reduce fc2 k-halves (waves wh and wh+4), store out[64][10] ----
  __syncthreads();
  float* red = (float*)&H[0];
  if (kh == 1) {
#pragma unroll
    for (int j = 0; j < 4; ++j)
      red[(wh * 16 + (lane >> 4) * 4 + j) * 16 + (lane & 15)] = acc2[j];
  }
  __syncthreads();
  if (kh == 0 && (lane & 15) < 10) {
#pragma unroll
    for (int j = 0; j < 4; ++j) {
      int rl = wh * 16 + (lane >> 4) * 4 + j;
      out[(row0 + rl) * 10 + (lane & 15)] = acc2[j] + red[rl * 16 + (lane & 15)];
    }
  }
}

extern "C" void kernel_launch(void* const* d_in, const int* in_sizes, int n_in,
                              void* d_out, int out_size, void* d_ws, size_t ws_size,
                              hipStream_t stream) {
  const float* x  = (const float*)d_in[0];
  const float* w1 = (const float*)d_in[1];
  const float* w2 = (const float*)d_in[2];
  float* out = (float*)d_out;

  unsigned char* w1qb = (unsigned char*)d_ws;             // blocked, 3.4MB
  unsigned char* w2q  = w1qb + (size_t)DH * KP;           // [16][4096]

  quant_w1_k<<<(DH * 52) / 256, 256, 0, stream>>>(w1, w1qb);
  quant_w2_k<<<16, 256, 0, stream>>>(w2, w2q);
  fused_mlp<<<32768 / MROWS, 512, 0, stream>>>(x, w1qb, w2q, out);
}